// Round 11
// baseline (421.625 us; speedup 1.0000x reference)
//
#include <hip/hip_runtime.h>
#include <cstdint>
#include <cstddef>

#define B_SZ 16384
#define X_D  64
#define U_D  16
#define Z_D  32
#define H_D  1024
#define A_D  256
#define DT_C 0.02f

typedef _Float16 f16;
typedef f16   f16x8 __attribute__((ext_vector_type(8)));
typedef f16   f16x4 __attribute__((ext_vector_type(4)));
typedef float f32x4 __attribute__((ext_vector_type(4)));
typedef float f32x16 __attribute__((ext_vector_type(16)));

#define AS1 __attribute__((address_space(1)))
#define AS3 __attribute__((address_space(3)))

__device__ __forceinline__ void gld_lds16(const void* g, void* l) {
    __builtin_amdgcn_global_load_lds((AS1 void*)(g), (AS3 void*)(l), 16, 0, 0);
}

#define BARX()  do { asm volatile("" ::: "memory"); __builtin_amdgcn_s_barrier(); \
                     asm volatile("" ::: "memory"); } while (0)
#define LGK0()  do { asm volatile("s_waitcnt lgkmcnt(0)" ::: "memory"); \
                     __builtin_amdgcn_sched_barrier(0); } while (0)
#define WAITV0() asm volatile("s_waitcnt vmcnt(0)" ::: "memory")

struct GArg {
    const f16*  A;     // [M, lda] activations (row-major subview)
    const f16*  W;     // [N, K]   transposed weights, ld == K
    const float* bias; // [N]
    void*       C;     // output
    int lda, ldc, K;
};
// Up to 3 sub-GEMMs in one launch; yn0/yn1 = #N-tiles of sub-GEMM 0/1.
struct GSet { GArg g[3]; int yn0, yn1; };

// d4 tail fusion args (used by gemm10_k<.,true>)
struct D4Tail {
    const f16*  w4t;   // [64][1024]
    const float* b4;   // [64]
    float*      out;   // [B][64]
    int*        cnt;   // [64] per-x-tile completion counters (prep-zeroed)
};

// ---------------------------------------------------------------------------
// R0 kernel (verified best for small-K launches): 128x128x64 block,
// single 32KB stage buffer (5 blocks/CU), 32x32x16 MFMA. Used for L1.
// ---------------------------------------------------------------------------
template<int BM,int BN,int BK,int WM,int WN,bool SILU,int OM>
__launch_bounds__(256)
__global__ void gemm_k(GSet p)
{
    static_assert(OM != 1 || BN == 128, "OM1 repack assumes BN=128");
    int yb = blockIdx.y, gi = 0;
    if (yb >= p.yn0) { yb -= p.yn0; gi = 1; if (yb >= p.yn1) { yb -= p.yn1; gi = 2; } }
    const GArg ga = p.g[gi];

    constexpr int SEGROW = BK / 8;
    constexpr int SMASK  = (SEGROW < 8 ? SEGROW : 8) - 1;
    constexpr int WTM = BM / WM, WTN = BN / WN;
    static_assert(WTM % 32 == 0 && WTN % 32 == 0, "wave tile in 32x32 units");
    constexpr int RM = WTM / 32, RN = WTN / 32;
    constexpr int KS = BK / 16;
    constexpr int ITA = (BM * SEGROW) / 256;
    constexpr int ITB = (BN * SEGROW) / 256;

    constexpr int STAGE_B = (BM + BN) * BK * 2;
    constexpr int CS_B    = (OM == 1) ? BM * BN * 2 : 0;
    constexpr int SMEM_B  = STAGE_B > CS_B ? STAGE_B : CS_B;
    __shared__ __align__(16) char smem[SMEM_B];
    f16* As = (f16*)smem;
    f16* Bs = As + BM * BK;

    const int tid  = threadIdx.x;
    const int lane = tid & 63;
    const int wave = tid >> 6;
    const int wm = wave / WN, wn = wave % WN;
    const int l31 = lane & 31, half = lane >> 5;

    const size_t arow0 = (size_t)blockIdx.x * BM;
    const size_t brow0 = (size_t)yb * BN;
    const int lda = ga.lda, K = ga.K;

    const f16* aptr[ITA];
    const f16* bptr[ITB];
#pragma unroll
    for (int it = 0; it < ITA; ++it) {
        int s = it * 256 + tid;
        int row = s / SEGROW, st = s % SEGROW;
        int sg = st ^ (row & SMASK);
        aptr[it] = ga.A + (arow0 + row) * lda + sg * 8;
    }
#pragma unroll
    for (int it = 0; it < ITB; ++it) {
        int s = it * 256 + tid;
        int row = s / SEGROW, st = s % SEGROW;
        int sg = st ^ (row & SMASK);
        bptr[it] = ga.W + (brow0 + row) * K + sg * 8;
    }

    f32x16 acc[RM][RN];
#pragma unroll
    for (int i = 0; i < RM; ++i)
#pragma unroll
        for (int j = 0; j < RN; ++j)
#pragma unroll
            for (int r = 0; r < 16; ++r) acc[i][j][r] = 0.f;

    for (int k0 = 0; k0 < K; k0 += BK) {
#pragma unroll
        for (int it = 0; it < ITA; ++it) {
            gld_lds16(aptr[it], &As[(it * 256 + tid) * 8]);
            aptr[it] += BK;
        }
#pragma unroll
        for (int it = 0; it < ITB; ++it) {
            gld_lds16(bptr[it], &Bs[(it * 256 + tid) * 8]);
            bptr[it] += BK;
        }
        __syncthreads();

#pragma unroll
        for (int ks = 0; ks < KS; ++ks) {
            f16x8 af[RM], bf[RN];
#pragma unroll
            for (int i = 0; i < RM; ++i) {
                int row = wm * WTM + i * 32 + l31;
                int st  = (ks * 2 + half) ^ (row & SMASK);
                af[i] = *(const f16x8*)&As[(row * SEGROW + st) * 8];
            }
#pragma unroll
            for (int j = 0; j < RN; ++j) {
                int row = wn * WTN + j * 32 + l31;
                int st  = (ks * 2 + half) ^ (row & SMASK);
                bf[j] = *(const f16x8*)&Bs[(row * SEGROW + st) * 8];
            }
#pragma unroll
            for (int i = 0; i < RM; ++i)
#pragma unroll
                for (int j = 0; j < RN; ++j)
                    acc[i][j] = __builtin_amdgcn_mfma_f32_32x32x16_f16(
                        af[i], bf[j], acc[i][j], 0, 0, 0);
        }
        __syncthreads();
    }

    const int rowbL = wm * WTM;
    const int colbL = wn * WTN;

    if constexpr (OM == 1) {
        f16* Cs = (f16*)smem;
#pragma unroll
        for (int j = 0; j < RN; ++j) {
            int colL = colbL + j * 32 + l31;
            float bv = ga.bias[(int)brow0 + colL];
            int chL = colL >> 3, wi = colL & 7;
#pragma unroll
            for (int i = 0; i < RM; ++i) {
#pragma unroll
                for (int r = 0; r < 16; ++r) {
                    int rowL = rowbL + i * 32 + (r & 3) + 8 * (r >> 2) + 4 * half;
                    float v = acc[i][j][r] + bv;
                    if (SILU) v = v / (1.0f + __expf(-v));
                    Cs[rowL * BN + ((chL ^ (rowL & 15)) << 3) + wi] = (f16)v;
                }
            }
        }
        __syncthreads();
        f16* Cout = (f16*)ga.C;
#pragma unroll
        for (int pass = 0; pass < (BM * BN / 8) / 256; ++pass) {
            int s = pass * 256 + tid;
            int rowL = s >> 4;
            int ch = s & 15;
            f16x8 v = *(const f16x8*)&Cs[rowL * BN + ((ch ^ (rowL & 15)) << 3)];
            *(f16x8*)&Cout[(size_t)(arow0 + rowL) * ga.ldc + brow0 + ch * 8] = v;
        }
    } else {
        float* Cout = (float*)ga.C;
#pragma unroll
        for (int j = 0; j < RN; ++j) {
            int col = (int)brow0 + colbL + j * 32 + l31;
            float bv = ga.bias[col];
#pragma unroll
            for (int i = 0; i < RM; ++i) {
#pragma unroll
                for (int r = 0; r < 16; ++r) {
                    int row = (int)arow0 + rowbL + i * 32
                            + (r & 3) + 8 * (r >> 2) + 4 * half;
                    float v = acc[i][j][r] + bv;
                    if (SILU) v = v / (1.0f + __expf(-v));
                    Cout[(size_t)row * ga.ldc + col] = v;
                }
            }
        }
    }
}

// ---------------------------------------------------------------------------
// gemm10_k (R8 structure, unchanged main loop): m201-form 256x256x64, 512
// thr = 8 waves (2M x 4N), wave tile 128x64, 16x16x32 MFMA, 2x64KB LDS dbuf,
// 4 C-quadrant phases/tile, zero-conflict slot-XOR swizzle.
// NEW (TAIL=true, d3 only): last-block d4 tail. After the epilogue each
// block: __threadfence (release) -> atomicAdd cnt[x]. The block seeing
// prev==3 acquires (__threadfence) and computes d4 for rows [x*256,+256):
// w4t (64x1024 = 128KB) staged into the dead LDS with the usual XOR
// swizzle; A-frags read from h3d (= ga.C) via global; verified 16x16x32
// fragment math (lane: row=l15, k=quad*8) and C/D map (row=quad*4+r,
// col=l15). No spinning (no deadlock); cnt re-zeroed by prep each replay.
// ---------------------------------------------------------------------------
template<bool SILU, bool TAIL>
__launch_bounds__(512, 2)
__global__ void gemm10_k(GSet p, D4Tail ta)
{
    int yb = blockIdx.y, gi = 0;
    if (yb >= p.yn0) { yb -= p.yn0; gi = 1; if (yb >= p.yn1) { yb -= p.yn1; gi = 2; } }
    const GArg ga = p.g[gi];

    __shared__ __align__(16) char smem[131072];   // 2 x {A 32K | B 32K}

    const int tid  = threadIdx.x;
    const int lane = tid & 63, wave = tid >> 6;
    const int wm = wave >> 2, wn = wave & 3;      // 2M x 4N
    const int l15 = lane & 15, quad = lane >> 4;

    const size_t arow0 = (size_t)blockIdx.x * 256;
    const size_t brow0 = (size_t)yb * 256;
    const int lda = ga.lda, K = ga.K;
    const int nt = K >> 6;

    const f16* spA[4];
    const f16* spB[4];
#pragma unroll
    for (int q = 0; q < 4; ++q) {
        int s = q * 512 + tid;
        int row = s >> 3;
        int kseg = (s & 7) ^ (row & 7);
        spA[q] = ga.A + (arow0 + row) * lda + kseg * 8;
        spB[q] = ga.W + (brow0 + row) * K + kseg * 8;
    }

    f32x4 acc[8][4];
#pragma unroll
    for (int i = 0; i < 8; ++i)
#pragma unroll
        for (int j = 0; j < 4; ++j)
#pragma unroll
            for (int r = 0; r < 4; ++r) acc[i][j][r] = 0.f;

    auto stageA = [&](char* buf, int q) {
        gld_lds16(spA[q], buf + (size_t)(q * 512 + tid) * 16);
        spA[q] += 64;
    };
    auto stageB = [&](char* buf, int q) {
        gld_lds16(spB[q], buf + 32768 + (size_t)(q * 512 + tid) * 16);
        spB[q] += 64;
    };

    f16x8 af[4][2], bf[2][2];
    auto readA = [&](const char* buf, int mh) {
#pragma unroll
        for (int i = 0; i < 4; ++i) {
            int ar = wm * 128 + mh * 64 + i * 16 + l15;
#pragma unroll
            for (int ks = 0; ks < 2; ++ks) {
                int st = (ks * 4 + quad) ^ (ar & 7);
                af[i][ks] = *(const f16x8*)(buf + ar * 128 + st * 16);
            }
        }
    };
    auto readB = [&](const char* buf, int nh) {
#pragma unroll
        for (int j = 0; j < 2; ++j) {
            int br = wn * 64 + nh * 32 + j * 16 + l15;
#pragma unroll
            for (int ks = 0; ks < 2; ++ks) {
                int st = (ks * 4 + quad) ^ (br & 7);
                bf[j][ks] = *(const f16x8*)(buf + 32768 + br * 128 + st * 16);
            }
        }
    };
    auto mma = [&](int mh, int nh) {
        __builtin_amdgcn_s_setprio(1);
#pragma unroll
        for (int ks = 0; ks < 2; ++ks)
#pragma unroll
            for (int i = 0; i < 4; ++i)
#pragma unroll
                for (int j = 0; j < 2; ++j)
                    acc[mh * 4 + i][nh * 2 + j] =
                        __builtin_amdgcn_mfma_f32_16x16x32_f16(
                            af[i][ks], bf[j][ks], acc[mh * 4 + i][nh * 2 + j],
                            0, 0, 0);
        __builtin_amdgcn_s_setprio(0);
    };

    // Prologue: stage tile 0 into buf0, drain (cold latency paid once).
    {
        char* b0 = smem;
        stageB(b0, 0); stageB(b0, 1); stageB(b0, 2); stageB(b0, 3);
        stageA(b0, 0); stageA(b0, 1); stageA(b0, 2); stageA(b0, 3);
        WAITV0();
        BARX();
    }

    for (int t = 0; t < nt; ++t) {
        char* buf  = smem + (size_t)(t & 1) * 65536;
        char* nbuf = smem + (size_t)((t & 1) ^ 1) * 65536;
        const bool st = (t + 1 < nt);
        // P1 (mh0, nh0): 12 reads + 4 B-stages
        readA(buf, 0); readB(buf, 0);
        if (st) { stageB(nbuf, 0); stageB(nbuf, 1); stageB(nbuf, 2); stageB(nbuf, 3); }
        BARX(); LGK0(); mma(0, 0); BARX();
        // P2 (mh0, nh1): 4 reads + 4 A-stages
        readB(buf, 1);
        if (st) { stageA(nbuf, 0); stageA(nbuf, 1); stageA(nbuf, 2); stageA(nbuf, 3); }
        BARX(); LGK0(); mma(0, 1); BARX();
        // P3 (mh1, nh1): 8 reads
        readA(buf, 1);
        BARX(); LGK0(); mma(1, 1); BARX();
        // P4 (mh1, nh0): 4 reads; wait covers loads issued >=2 phases ago
        readB(buf, 0);
        if (st) WAITV0();
        BARX(); LGK0(); mma(1, 0); BARX();
    }

    // ---- epilogue: bias + SiLU, f16 repack via LDS (buffers dead) ----
    f16* Cs = (f16*)smem;
#pragma unroll
    for (int mf = 0; mf < 8; ++mf)
#pragma unroll
        for (int nf = 0; nf < 4; ++nf) {
            int colL = wn * 64 + (nf >> 1) * 32 + (nf & 1) * 16 + l15;
            float bv = ga.bias[(int)brow0 + colL];
            int ch = colL >> 3, wi = colL & 7;
#pragma unroll
            for (int r = 0; r < 4; ++r) {
                int rowL = wm * 128 + (mf >> 2) * 64 + (mf & 3) * 16 + quad * 4 + r;
                float v = acc[mf][nf][r] + bv;
                if (SILU) v = v / (1.0f + __expf(-v));
                Cs[rowL * 256 + ((ch ^ (rowL & 31)) << 3) + wi] = (f16)v;
            }
        }
    __syncthreads();
    f16* Cout = (f16*)ga.C;
#pragma unroll
    for (int pass = 0; pass < 16; ++pass) {
        int s = pass * 512 + tid;
        int rowL = s >> 5, ch = s & 31;
        f16x8 v = *(const f16x8*)&Cs[rowL * 256 + ((ch ^ (rowL & 31)) << 3)];
        *(f16x8*)&Cout[(size_t)(arow0 + rowL) * ga.ldc + brow0 + ch * 8] = v;
    }

    if constexpr (TAIL) {
        // ---- release: my h3d stores visible before my counter bump ----
        __threadfence();
        __syncthreads();
        if (tid == 0) {
            int prev = atomicAdd(ta.cnt + blockIdx.x, 1);
            *(volatile int*)smem = (prev == 3) ? 1 : 0;
        }
        __syncthreads();
        int last = *(volatile int*)smem;
        if (!last) return;
        __threadfence();   // acquire: other blocks' h3d stores visible

        // ---- stage w4t [64][1024] -> LDS 128KB, slot-low3 XOR swizzle ----
        __syncthreads();   // all threads past flag read before overwrite
#pragma unroll
        for (int q = 0; q < 16; ++q) {
            int s = q * 512 + tid;
            int row = s >> 7, sl = s & 127;
            int ssrc = (sl & ~7) | ((sl & 7) ^ (row & 7));
            gld_lds16(ta.w4t + (size_t)row * 1024 + ssrc * 8,
                      smem + (size_t)s * 16);
        }
        WAITV0();
        BARX();

        // ---- d4: out[256x64] = h3d[256x1024] @ w4^T + b4 (f32, no act) ----
        const size_t xr0 = (size_t)blockIdx.x * 256 + (size_t)wave * 32;
        const f16* hbase = (const f16*)ga.C + xr0 * 1024;
        f32x4 accd[2][4];
#pragma unroll
        for (int i = 0; i < 2; ++i)
#pragma unroll
            for (int n = 0; n < 4; ++n)
#pragma unroll
                for (int r = 0; r < 4; ++r) accd[i][n][r] = 0.f;

        for (int ks = 0; ks < 32; ++ks) {
            int k0 = ks * 32;
            f16x8 afr[2];
#pragma unroll
            for (int i = 0; i < 2; ++i)
                afr[i] = *(const f16x8*)&hbase[(size_t)(i * 16 + l15) * 1024
                                               + k0 + quad * 8];
#pragma unroll
            for (int n = 0; n < 4; ++n) {
                int col = n * 16 + l15;
                int slot = (k0 >> 3) + quad;
                int sl2 = (slot & ~7) | ((slot & 7) ^ (col & 7));
                f16x8 bfr = *(const f16x8*)(smem + (size_t)col * 2048 + sl2 * 16);
#pragma unroll
                for (int i = 0; i < 2; ++i)
                    accd[i][n] = __builtin_amdgcn_mfma_f32_16x16x32_f16(
                        afr[i], bfr, accd[i][n], 0, 0, 0);
            }
        }
#pragma unroll
        for (int n = 0; n < 4; ++n) {
            int col = n * 16 + l15;
            float bv = ta.b4[col];
#pragma unroll
            for (int i = 0; i < 2; ++i)
#pragma unroll
                for (int r = 0; r < 4; ++r) {
                    size_t row = xr0 + i * 16 + quad * 4 + r;
                    ta.out[row * 64 + col] = accd[i][n][r] + bv;
                }
        }
    }
}

// ---------------------------------------------------------------------------
// Fused middle: e3 + a3 + b3 + Bu + Koopman + d1 -> h1d [B,1024] f16.
// (R10, verified; unchanged.)
// ---------------------------------------------------------------------------
__launch_bounds__(256)
__global__ void mid_k(const f16* __restrict__ cc2,
                      const f16* __restrict__ e_w3t, const float* __restrict__ e_b3,
                      const f16* __restrict__ a_w3t, const float* __restrict__ a_b3,
                      const f16* __restrict__ b_w3t, const float* __restrict__ b_b3,
                      const f16* __restrict__ d_w1t, const float* __restrict__ d_b1,
                      const float* __restrict__ u,   f16* __restrict__ h1d)
{
    __shared__ __align__(16) f16 As[32 * 64];
    __shared__ __align__(16) f16 Bs[128 * 64];
    __shared__ __align__(16) f16 zs[32 * 32];
    __shared__ float zb[32 * 32];
    __shared__ float ab[32 * 32];
    __shared__ float bu[32 * 32];
    __shared__ float ub[32 * 16];

    const int tid  = threadIdx.x;
    const int lane = tid & 63, wave = tid >> 6;
    const int l15 = lane & 15, quad = lane >> 4;
    const int r0 = blockIdx.x * 32;

    ub[tid]       = u[r0 * 16 + tid];
    ub[tid + 256] = u[r0 * 16 + 256 + tid];

    auto stage_d1 = [&](int ch) {
#pragma unroll
        for (int q = 0; q < 4; ++q) {
            int s = q * 256 + tid;
            int row = s >> 2, j = s & 3;
            int kseg = j ^ (row & 3);
            gld_lds16(d_w1t + (size_t)(ch * 256 + row) * 32 + kseg * 8,
                      &Bs[s * 8]);
        }
    };

#pragma unroll 1
    for (int ph = 0; ph < 2; ++ph) {
        const f16* W    = ph ? a_w3t : e_w3t;
        const float* bs = ph ? a_b3 : e_b3;
        const int K     = ph ? 256 : 1024;
        const int co    = ph ? 1024 : 0;
        float* ob       = ph ? ab : zb;
        f32x4 acc = {0.f, 0.f, 0.f, 0.f};
        for (int k0 = 0; k0 < K; k0 += 64) {
            {
                int row = tid >> 3, sg = (tid & 7) ^ (row & 7);
                gld_lds16(cc2 + (size_t)(r0 + row) * 1536 + co + k0 + sg * 8,
                          &As[tid * 8]);
            }
            {
                int row = tid >> 3, sg = (tid & 7) ^ (row & 7);
                gld_lds16(W + (size_t)row * K + k0 + sg * 8, &Bs[tid * 8]);
            }
            __syncthreads();
#pragma unroll
            for (int kk = 0; kk < 64; kk += 32) {
                int ar = ((wave >> 1) << 4) + l15;
                int ast = ((kk >> 3) + quad) ^ (ar & 7);
                f16x8 af = *(const f16x8*)&As[(ar * 8 + ast) * 8];
                int br = ((wave & 1) << 4) + l15;
                int bst = ((kk >> 3) + quad) ^ (br & 7);
                f16x8 bf = *(const f16x8*)&Bs[(br * 8 + bst) * 8];
                acc = __builtin_amdgcn_mfma_f32_16x16x32_f16(af, bf, acc, 0, 0, 0);
            }
            __syncthreads();
        }
#pragma unroll
        for (int r = 0; r < 4; ++r) {
            int row = ((wave >> 1) << 4) + quad * 4 + r;
            int col = ((wave & 1) << 4) + l15;
            ob[row * 32 + col] = acc[r] + bs[col];
        }
    }

#pragma unroll 1
    for (int ch = 0; ch < 4; ++ch) {
        f32x4 acc[2][2];
#pragma unroll
        for (int i = 0; i < 2; ++i)
#pragma unroll
            for (int j = 0; j < 2; ++j) acc[i][j] = f32x4{0.f, 0.f, 0.f, 0.f};
        for (int k0 = 0; k0 < 256; k0 += 64) {
            {   int row = tid >> 3, sg = (tid & 7) ^ (row & 7);
                gld_lds16(cc2 + (size_t)(r0 + row) * 1536 + 1280 + k0 + sg * 8,
                          &As[tid * 8]);
            }
#pragma unroll
            for (int it = 0; it < 4; ++it) {
                int s = it * 256 + tid;
                int row = s >> 3, sg = (s & 7) ^ (row & 7);
                gld_lds16(b_w3t + (size_t)(ch * 128 + row) * 256 + k0 + sg * 8,
                          &Bs[s * 8]);
            }
            __syncthreads();
#pragma unroll
            for (int kk = 0; kk < 64; kk += 32) {
                f16x8 af[2], bf[2];
#pragma unroll
                for (int i = 0; i < 2; ++i) {
                    int ar = i * 16 + l15;
                    int st = ((kk >> 3) + quad) ^ (ar & 7);
                    af[i] = *(const f16x8*)&As[(ar * 8 + st) * 8];
                }
#pragma unroll
                for (int j = 0; j < 2; ++j) {
                    int br = wave * 32 + j * 16 + l15;
                    int st = ((kk >> 3) + quad) ^ (br & 7);
                    bf[j] = *(const f16x8*)&Bs[(br * 8 + st) * 8];
                }
#pragma unroll
                for (int i = 0; i < 2; ++i)
#pragma unroll
                    for (int j = 0; j < 2; ++j)
                        acc[i][j] = __builtin_amdgcn_mfma_f32_16x16x32_f16(
                            af[i], bf[j], acc[i][j], 0, 0, 0);
            }
            __syncthreads();
        }
#pragma unroll
        for (int j = 0; j < 2; ++j) {
            int colg = ch * 128 + wave * 32 + j * 16 + l15;
            float bv = b_b3[colg];
            int z = colg >> 4;
#pragma unroll
            for (int i = 0; i < 2; ++i) {
#pragma unroll
                for (int r = 0; r < 4; ++r) {
                    int row = i * 16 + quad * 4 + r;
                    float v = (acc[i][j][r] + bv) * ub[row * 16 + l15];
                    v += __shfl_xor(v, 8, 16);
                    v += __shfl_xor(v, 4, 16);
                    v += __shfl_xor(v, 2, 16);
                    v += __shfl_xor(v, 1, 16);
                    if (l15 == 0) bu[row * 32 + z] = v;
                }
            }
        }
    }
    __syncthreads();

    stage_d1(0);
#pragma unroll
    for (int t = 0; t < 4; ++t) {
        int idx = t * 256 + tid;
        int row = idx >> 5, z = idx & 31;
        int pb = idx & ~1;
        float a  = ab[pb], b = ab[pb + 1];
        float z0 = zb[pb], z1 = zb[pb + 1];
        float f  = __expf(a * DT_C);
        float c_ = __cosf(b * DT_C);
        float s_ = __sinf(b * DT_C);
        float Az = (z & 1) ? f * (s_ * z0 + c_ * z1) : f * (c_ * z0 - s_ * z1);
        float zc = (z & 1) ? z1 : z0;
        f16 zv = (f16)(zc + DT_C * (Az + bu[idx]));
        zs[(row * 4 + ((z >> 3) ^ (row & 3))) * 8 + (z & 7)] = zv;
    }
    __syncthreads();

    f16x8 afD[2];
#pragma unroll
    for (int i = 0; i < 2; ++i) {
        int ar = i * 16 + l15;
        int ast = quad ^ (ar & 3);
        afD[i] = *(const f16x8*)&zs[(ar * 4 + ast) * 8];
    }
#pragma unroll 1
    for (int ch = 0; ch < 4; ++ch) {
        f32x4 accd[2][4];
#pragma unroll
        for (int n = 0; n < 4; ++n) {
            int br = wave * 64 + n * 16 + l15;
            int bst = quad ^ (br & 3);
            f16x8 bf = *(const f16x8*)&Bs[(br * 4 + bst) * 8];
#pragma unroll
            for (int i = 0; i < 2; ++i) {
                f32x4 zero = {0.f, 0.f, 0.f, 0.f};
                accd[i][n] = __builtin_amdgcn_mfma_f32_16x16x32_f16(
                    afD[i], bf, zero, 0, 0, 0);
            }
        }
        __syncthreads();
        if (ch < 3) stage_d1(ch + 1);
#pragma unroll
        for (int n = 0; n < 4; ++n) {
            int col = ch * 256 + wave * 64 + n * 16 + l15;
            float bv = d_b1[col];
#pragma unroll
            for (int i = 0; i < 2; ++i)
#pragma unroll
                for (int r = 0; r < 4; ++r) {
                    int row = i * 16 + quad * 4 + r;
                    float v = accd[i][n][r] + bv;
                    v = v / (1.0f + __expf(-v));
                    h1d[(size_t)(r0 + row) * 1024 + col] = (f16)v;
                }
        }
        if (ch < 3) __syncthreads();
    }
}

// ---------------------------------------------------------------------------
// One-shot prep: 13 weight transposes (f32 [K,N] -> f16 [N,K]), x f32->f16,
// L1 bias concat, d4-tail counter zeroing.
// ---------------------------------------------------------------------------
struct PrepArgs {
    const float* w[13];
    f16*         wt[13];
    int          K[13];
    int          N[13];
    const float* bsrc[3];
    float*       bias1;
    const float* x;
    f16*         xb;
    int*         cnt;   // [64] d4-tail counters (zeroed every replay)
};

__launch_bounds__(256)
__global__ void prep_k(PrepArgs pa, int ntrans, int ncvt)
{
    int bid = blockIdx.x;
    if (bid < ntrans) {
        int i = 0, t;
        for (;; ++i) {
            t = (pa.K[i] >> 5) * (pa.N[i] >> 5);
            if (bid < t) break;
            bid -= t;
        }
        const int K = pa.K[i], N = pa.N[i];
        const int tn = N >> 5;
        const int k0 = (bid / tn) << 5, n0 = (bid % tn) << 5;
        __shared__ float tbuf[32][33];
        const int tx = threadIdx.x & 31, ty = threadIdx.x >> 5;
        const float* src = pa.w[i];
        f16* dst = pa.wt[i];
#pragma unroll
        for (int r = 0; r < 32; r += 8)
            tbuf[ty + r][tx] = src[(size_t)(k0 + ty + r) * N + n0 + tx];
        __syncthreads();
#pragma unroll
        for (int r = 0; r < 32; r += 8)
            dst[(size_t)(n0 + ty + r) * K + k0 + tx] = (f16)tbuf[tx][ty + r];
    } else if (bid < ntrans + ncvt) {
        int i = ((bid - ntrans) * 256 + threadIdx.x) * 4;
        float4 v = *(const float4*)(pa.x + i);
        f16x4 o = {(f16)v.x, (f16)v.y, (f16)v.z, (f16)v.w};
        *(f16x4*)(pa.xb + i) = o;
    } else {
        int idx = (bid - ntrans - ncvt) * 256 + (int)threadIdx.x; // 0..1535
        float v = (idx < 1024) ? pa.bsrc[0][idx]
                : (idx < 1280) ? pa.bsrc[1][idx - 1024]
                               : pa.bsrc[2][idx - 1280];
        pa.bias1[idx] = v;
        if (idx < 64) pa.cnt[idx] = 0;
    }
}

extern "C" void kernel_launch(void* const* d_in, const int* in_sizes, int n_in,
                              void* d_out, int out_size, void* d_ws, size_t ws_size,
                              hipStream_t stream)
{
    (void)in_sizes; (void)n_in; (void)out_size; (void)ws_size;
    const float* x    = (const float*)d_in[0];
    const float* u    = (const float*)d_in[1];
    const float* e_w1 = (const float*)d_in[2];  const float* e_b1 = (const float*)d_in[3];
    const float* e_w2 = (const float*)d_in[4];  const float* e_b2 = (const float*)d_in[5];
    const float* e_w3 = (const float*)d_in[6];  const float* e_b3 = (const float*)d_in[7];
    const float* d_w1 = (const float*)d_in[8];  const float* d_b1 = (const float*)d_in[9];
    const float* d_w2 = (const float*)d_in[10]; const float* d_b2 = (const float*)d_in[11];
    const float* d_w3 = (const float*)d_in[12]; const float* d_b3 = (const float*)d_in[13];
    const float* d_w4 = (const float*)d_in[14]; const float* d_b4 = (const float*)d_in[15];
    const float* a_w1 = (const float*)d_in[16]; const float* a_b1 = (const float*)d_in[17];
    const float* a_w2 = (const float*)d_in[18]; const float* a_b2 = (const float*)d_in[19];
    const float* a_w3 = (const float*)d_in[20]; const float* a_b3 = (const float*)d_in[21];
    const float* b_w1 = (const float*)d_in[22]; const float* b_b1 = (const float*)d_in[23];
    const float* b_w2 = (const float*)d_in[24]; const float* b_b2 = (const float*)d_in[25];
    const float* b_w3 = (const float*)d_in[26]; const float* b_b3 = (const float*)d_in[27];

    char* p = (char*)d_ws;
    auto alloc = [&](size_t nbytes) -> void* {
        void* r = (void*)p;
        p += (nbytes + 255) & ~(size_t)255;
        return r;
    };
    // activations
    f16*   xb   = (f16*)  alloc((size_t)B_SZ * X_D * 2);
    f16*   cc1  = (f16*)  alloc((size_t)B_SZ * 1536 * 2);  // h1e | p1a | p1b
    f16*   cc2  = (f16*)  alloc((size_t)B_SZ * 1536 * 2);  // h2e | p2a | p2b
    // decoder ping-pong aliases (cc1/cc2 dead by then)
    f16*   h1d  = cc1;
    f16*   h2d  = cc2;
    f16*   h3d  = cc1;
    // transposed f16 weights [N][K]
    f16*   W1t   = (f16*)alloc((size_t)1536 * X_D * 2);    // e|a|b layer-1 stacked
    float* bias1 = (float*)alloc(1536 * 4);
    f16* e_w2t = (f16*)alloc((size_t)H_D * H_D * 2);
    f16* e_w3t = (f16*)alloc((size_t)Z_D * H_D * 2);
    f16* d_w1t = (f16*)alloc((size_t)H_D * Z_D * 2);
    f16* d_w2t = (f16*)alloc((size_t)H_D * H_D * 2);
    f16* d_w3t = (f16*)alloc((size_t)H_D * H_D * 2);
    f16* d_w4t = (f16*)alloc((size_t)X_D * H_D * 2);
    f16* a_w2t = (f16*)alloc((size_t)A_D * A_D * 2);
    f16* a_w3t = (f16*)alloc((size_t)Z_D * A_D * 2);
    f16* b_w2t = (f16*)alloc((size_t)A_D * A_D * 2);
    f16* b_w3t = (f16*)alloc((size_t)(Z_D * U_D) * A_D * 2);
    int* d4cnt = (int*)alloc(64 * 4);

    // ---- prep ----
    PrepArgs pa;
    const float* ws_[13] = {e_w1, e_w2, e_w3, d_w1, d_w2, d_w3, d_w4,
                            a_w1, a_w2, a_w3, b_w1, b_w2, b_w3};
    f16* wts_[13] = {W1t, e_w2t, e_w3t, d_w1t, d_w2t, d_w3t, d_w4t,
                     W1t + (size_t)1024 * X_D, a_w2t, a_w3t,
                     W1t + (size_t)1280 * X_D, b_w2t, b_w3t};
    int Ks_[13] = {X_D, H_D, H_D, Z_D, H_D, H_D, H_D, X_D, A_D, A_D, X_D, A_D, A_D};
    int Ns_[13] = {H_D, H_D, Z_D, H_D, H_D, H_D, X_D, A_D, A_D, Z_D, A_D, A_D, Z_D*U_D};
    int ntrans = 0;
    for (int i = 0; i < 13; ++i) {
        pa.w[i] = ws_[i]; pa.wt[i] = wts_[i]; pa.K[i] = Ks_[i]; pa.N[i] = Ns_[i];
        ntrans += (Ks_[i] >> 5) * (Ns_[i] >> 5);
    }
    pa.bsrc[0] = e_b1; pa.bsrc[1] = a_b1; pa.bsrc[2] = b_b1;
    pa.bias1 = bias1; pa.x = x; pa.xb = xb; pa.cnt = d4cnt;
    const int ncvt = (B_SZ * X_D) / 1024;
    prep_k<<<ntrans + ncvt + 6, 256, 0, stream>>>(pa, ntrans, ncvt);

    auto G = [](const f16* A, const f16* W, const float* bias, void* C,
                int lda, int ldc, int K) {
        GArg g; g.A = A; g.W = W; g.bias = bias; g.C = C;
        g.lda = lda; g.ldc = ldc; g.K = K; return g;
    };
    GSet s;
    D4Tail tz{};   // dummy for TAIL=false launches

    // ---- fused layer-1: [B,64] @ [64,1536] -> cc1 (K=64, old kernel) ----
    s.g[0] = G(xb, W1t, bias1, cc1, X_D, 1536, X_D);
    s.yn0 = 12; s.yn1 = 0;
    gemm_k<128,128,64,2,2,true,1><<<dim3(B_SZ/128, 12), 256, 0, stream>>>(s);

    // ---- merged layer-2 via m201-port: e2 (4 tiles) + a2 (1) + b2 (1) ----
    s.g[0] = G(cc1,        e_w2t, e_b2, cc2,        1536, 1536, H_D);
    s.g[1] = G(cc1 + 1024, a_w2t, a_b2, cc2 + 1024, 1536, 1536, A_D);
    s.g[2] = G(cc1 + 1280, b_w2t, b_b2, cc2 + 1280, 1536, 1536, A_D);
    s.yn0 = 4; s.yn1 = 1;
    gemm10_k<true,false><<<dim3(B_SZ/256, 6), 512, 0, stream>>>(s, tz);

    // ---- fused middle: e3+a3+b3+Bu+Koopman+d1 -> h1d ----
    mid_k<<<B_SZ/32, 256, 0, stream>>>(cc2, e_w3t, e_b3, a_w3t, a_b3,
                                       b_w3t, b_b3, d_w1t, d_b1, u, h1d);

    // ---- decoder: d2, then d3 with fused d4 last-block tail ----
    s.yn0 = 4; s.yn1 = 0;
    s.g[0] = G(h1d, d_w2t, d_b2, h2d, H_D, H_D, H_D);
    gemm10_k<true,false><<<dim3(B_SZ/256, 4), 512, 0, stream>>>(s, tz);

    s.g[0] = G(h2d, d_w3t, d_b3, h3d, H_D, H_D, H_D);
    D4Tail ta;
    ta.w4t = d_w4t; ta.b4 = d_b4; ta.out = (float*)d_out; ta.cnt = d4cnt;
    gemm10_k<true,true><<<dim3(B_SZ/256, 4), 512, 0, stream>>>(s, ta);
}

// Round 12
// 347.724 us; speedup vs baseline: 1.2125x; 1.2125x over previous
//
#include <hip/hip_runtime.h>
#include <cstdint>
#include <cstddef>

#define B_SZ 16384
#define X_D  64
#define U_D  16
#define Z_D  32
#define H_D  1024
#define A_D  256
#define DT_C 0.02f

typedef _Float16 f16;
typedef f16   f16x8 __attribute__((ext_vector_type(8)));
typedef f16   f16x4 __attribute__((ext_vector_type(4)));
typedef float f32x4 __attribute__((ext_vector_type(4)));
typedef float f32x16 __attribute__((ext_vector_type(16)));

#define AS1 __attribute__((address_space(1)))
#define AS3 __attribute__((address_space(3)))

__device__ __forceinline__ void gld_lds16(const void* g, void* l) {
    __builtin_amdgcn_global_load_lds((AS1 void*)(g), (AS3 void*)(l), 16, 0, 0);
}

#define BARX()  do { asm volatile("" ::: "memory"); __builtin_amdgcn_s_barrier(); \
                     asm volatile("" ::: "memory"); } while (0)
#define LGK0()  do { asm volatile("s_waitcnt lgkmcnt(0)" ::: "memory"); \
                     __builtin_amdgcn_sched_barrier(0); } while (0)
#define WAITV0() asm volatile("s_waitcnt vmcnt(0)" ::: "memory")

struct GArg {
    const f16*  A;     // [M, lda] activations (row-major subview)
    const f16*  W;     // [N, K]   transposed weights, ld == K
    const float* bias; // [N]
    void*       C;     // output
    int lda, ldc, K;
};
// Up to 3 sub-GEMMs in one launch; yn0/yn1 = #N-tiles of sub-GEMM 0/1.
struct GSet { GArg g[3]; int yn0, yn1; };

// ---------------------------------------------------------------------------
// R0 kernel (verified best for small-K launches): 128x128x64 block,
// single 32KB stage buffer (5 blocks/CU), 32x32x16 MFMA. Used for L1/d4.
// ---------------------------------------------------------------------------
template<int BM,int BN,int BK,int WM,int WN,bool SILU,int OM>
__launch_bounds__(256)
__global__ void gemm_k(GSet p)
{
    static_assert(OM != 1 || BN == 128, "OM1 repack assumes BN=128");
    int yb = blockIdx.y, gi = 0;
    if (yb >= p.yn0) { yb -= p.yn0; gi = 1; if (yb >= p.yn1) { yb -= p.yn1; gi = 2; } }
    const GArg ga = p.g[gi];

    constexpr int SEGROW = BK / 8;
    constexpr int SMASK  = (SEGROW < 8 ? SEGROW : 8) - 1;
    constexpr int WTM = BM / WM, WTN = BN / WN;
    static_assert(WTM % 32 == 0 && WTN % 32 == 0, "wave tile in 32x32 units");
    constexpr int RM = WTM / 32, RN = WTN / 32;
    constexpr int KS = BK / 16;
    constexpr int ITA = (BM * SEGROW) / 256;
    constexpr int ITB = (BN * SEGROW) / 256;

    constexpr int STAGE_B = (BM + BN) * BK * 2;
    constexpr int CS_B    = (OM == 1) ? BM * BN * 2 : 0;
    constexpr int SMEM_B  = STAGE_B > CS_B ? STAGE_B : CS_B;
    __shared__ __align__(16) char smem[SMEM_B];
    f16* As = (f16*)smem;
    f16* Bs = As + BM * BK;

    const int tid  = threadIdx.x;
    const int lane = tid & 63;
    const int wave = tid >> 6;
    const int wm = wave / WN, wn = wave % WN;
    const int l31 = lane & 31, half = lane >> 5;

    const size_t arow0 = (size_t)blockIdx.x * BM;
    const size_t brow0 = (size_t)yb * BN;
    const int lda = ga.lda, K = ga.K;

    const f16* aptr[ITA];
    const f16* bptr[ITB];
#pragma unroll
    for (int it = 0; it < ITA; ++it) {
        int s = it * 256 + tid;
        int row = s / SEGROW, st = s % SEGROW;
        int sg = st ^ (row & SMASK);
        aptr[it] = ga.A + (arow0 + row) * lda + sg * 8;
    }
#pragma unroll
    for (int it = 0; it < ITB; ++it) {
        int s = it * 256 + tid;
        int row = s / SEGROW, st = s % SEGROW;
        int sg = st ^ (row & SMASK);
        bptr[it] = ga.W + (brow0 + row) * K + sg * 8;
    }

    f32x16 acc[RM][RN];
#pragma unroll
    for (int i = 0; i < RM; ++i)
#pragma unroll
        for (int j = 0; j < RN; ++j)
#pragma unroll
            for (int r = 0; r < 16; ++r) acc[i][j][r] = 0.f;

    for (int k0 = 0; k0 < K; k0 += BK) {
#pragma unroll
        for (int it = 0; it < ITA; ++it) {
            gld_lds16(aptr[it], &As[(it * 256 + tid) * 8]);
            aptr[it] += BK;
        }
#pragma unroll
        for (int it = 0; it < ITB; ++it) {
            gld_lds16(bptr[it], &Bs[(it * 256 + tid) * 8]);
            bptr[it] += BK;
        }
        __syncthreads();

#pragma unroll
        for (int ks = 0; ks < KS; ++ks) {
            f16x8 af[RM], bf[RN];
#pragma unroll
            for (int i = 0; i < RM; ++i) {
                int row = wm * WTM + i * 32 + l31;
                int st  = (ks * 2 + half) ^ (row & SMASK);
                af[i] = *(const f16x8*)&As[(row * SEGROW + st) * 8];
            }
#pragma unroll
            for (int j = 0; j < RN; ++j) {
                int row = wn * WTN + j * 32 + l31;
                int st  = (ks * 2 + half) ^ (row & SMASK);
                bf[j] = *(const f16x8*)&Bs[(row * SEGROW + st) * 8];
            }
#pragma unroll
            for (int i = 0; i < RM; ++i)
#pragma unroll
                for (int j = 0; j < RN; ++j)
                    acc[i][j] = __builtin_amdgcn_mfma_f32_32x32x16_f16(
                        af[i], bf[j], acc[i][j], 0, 0, 0);
        }
        __syncthreads();
    }

    const int rowbL = wm * WTM;
    const int colbL = wn * WTN;

    if constexpr (OM == 1) {
        f16* Cs = (f16*)smem;
#pragma unroll
        for (int j = 0; j < RN; ++j) {
            int colL = colbL + j * 32 + l31;
            float bv = ga.bias[(int)brow0 + colL];
            int chL = colL >> 3, wi = colL & 7;
#pragma unroll
            for (int i = 0; i < RM; ++i) {
#pragma unroll
                for (int r = 0; r < 16; ++r) {
                    int rowL = rowbL + i * 32 + (r & 3) + 8 * (r >> 2) + 4 * half;
                    float v = acc[i][j][r] + bv;
                    if (SILU) v = v / (1.0f + __expf(-v));
                    Cs[rowL * BN + ((chL ^ (rowL & 15)) << 3) + wi] = (f16)v;
                }
            }
        }
        __syncthreads();
        f16* Cout = (f16*)ga.C;
#pragma unroll
        for (int pass = 0; pass < (BM * BN / 8) / 256; ++pass) {
            int s = pass * 256 + tid;
            int rowL = s >> 4;
            int ch = s & 15;
            f16x8 v = *(const f16x8*)&Cs[rowL * BN + ((ch ^ (rowL & 15)) << 3)];
            *(f16x8*)&Cout[(size_t)(arow0 + rowL) * ga.ldc + brow0 + ch * 8] = v;
        }
    } else {
        float* Cout = (float*)ga.C;
#pragma unroll
        for (int j = 0; j < RN; ++j) {
            int col = (int)brow0 + colbL + j * 32 + l31;
            float bv = ga.bias[col];
#pragma unroll
            for (int i = 0; i < RM; ++i) {
#pragma unroll
                for (int r = 0; r < 16; ++r) {
                    int row = (int)arow0 + rowbL + i * 32
                            + (r & 3) + 8 * (r >> 2) + 4 * half;
                    float v = acc[i][j][r] + bv;
                    if (SILU) v = v / (1.0f + __expf(-v));
                    Cout[(size_t)row * ga.ldc + col] = v;
                }
            }
        }
    }
}

// ---------------------------------------------------------------------------
// gemm10_k (R8 structure, best measured): m201-form 256x256x64, 512 thr = 8
// waves (2M x 4N), wave tile 128x64, 16x16x32 MFMA, 2x64KB LDS dbuf,
// 4 C-quadrant phases/tile, zero-conflict slot-XOR swizzle, covered
// vmcnt(0) at P4.
// ---------------------------------------------------------------------------
template<bool SILU>
__launch_bounds__(512, 2)
__global__ void gemm10_k(GSet p)
{
    int yb = blockIdx.y, gi = 0;
    if (yb >= p.yn0) { yb -= p.yn0; gi = 1; if (yb >= p.yn1) { yb -= p.yn1; gi = 2; } }
    const GArg ga = p.g[gi];

    __shared__ __align__(16) char smem[131072];   // 2 x {A 32K | B 32K}

    const int tid  = threadIdx.x;
    const int lane = tid & 63, wave = tid >> 6;
    const int wm = wave >> 2, wn = wave & 3;      // 2M x 4N
    const int l15 = lane & 15, quad = lane >> 4;

    const size_t arow0 = (size_t)blockIdx.x * 256;
    const size_t brow0 = (size_t)yb * 256;
    const int lda = ga.lda, K = ga.K;
    const int nt = K >> 6;

    const f16* spA[4];
    const f16* spB[4];
#pragma unroll
    for (int q = 0; q < 4; ++q) {
        int s = q * 512 + tid;
        int row = s >> 3;
        int kseg = (s & 7) ^ (row & 7);
        spA[q] = ga.A + (arow0 + row) * lda + kseg * 8;
        spB[q] = ga.W + (brow0 + row) * K + kseg * 8;
    }

    f32x4 acc[8][4];
#pragma unroll
    for (int i = 0; i < 8; ++i)
#pragma unroll
        for (int j = 0; j < 4; ++j)
#pragma unroll
            for (int r = 0; r < 4; ++r) acc[i][j][r] = 0.f;

    auto stageA = [&](char* buf, int q) {
        gld_lds16(spA[q], buf + (size_t)(q * 512 + tid) * 16);
        spA[q] += 64;
    };
    auto stageB = [&](char* buf, int q) {
        gld_lds16(spB[q], buf + 32768 + (size_t)(q * 512 + tid) * 16);
        spB[q] += 64;
    };

    f16x8 af[4][2], bf[2][2];
    auto readA = [&](const char* buf, int mh) {
#pragma unroll
        for (int i = 0; i < 4; ++i) {
            int ar = wm * 128 + mh * 64 + i * 16 + l15;
#pragma unroll
            for (int ks = 0; ks < 2; ++ks) {
                int st = (ks * 4 + quad) ^ (ar & 7);
                af[i][ks] = *(const f16x8*)(buf + ar * 128 + st * 16);
            }
        }
    };
    auto readB = [&](const char* buf, int nh) {
#pragma unroll
        for (int j = 0; j < 2; ++j) {
            int br = wn * 64 + nh * 32 + j * 16 + l15;
#pragma unroll
            for (int ks = 0; ks < 2; ++ks) {
                int st = (ks * 4 + quad) ^ (br & 7);
                bf[j][ks] = *(const f16x8*)(buf + 32768 + br * 128 + st * 16);
            }
        }
    };
    auto mma = [&](int mh, int nh) {
        __builtin_amdgcn_s_setprio(1);
#pragma unroll
        for (int ks = 0; ks < 2; ++ks)
#pragma unroll
            for (int i = 0; i < 4; ++i)
#pragma unroll
                for (int j = 0; j < 2; ++j)
                    acc[mh * 4 + i][nh * 2 + j] =
                        __builtin_amdgcn_mfma_f32_16x16x32_f16(
                            af[i][ks], bf[j][ks], acc[mh * 4 + i][nh * 2 + j],
                            0, 0, 0);
        __builtin_amdgcn_s_setprio(0);
    };

    // Prologue: stage tile 0 into buf0, drain (cold latency paid once).
    {
        char* b0 = smem;
        stageB(b0, 0); stageB(b0, 1); stageB(b0, 2); stageB(b0, 3);
        stageA(b0, 0); stageA(b0, 1); stageA(b0, 2); stageA(b0, 3);
        WAITV0();
        BARX();
    }

    for (int t = 0; t < nt; ++t) {
        char* buf  = smem + (size_t)(t & 1) * 65536;
        char* nbuf = smem + (size_t)((t & 1) ^ 1) * 65536;
        const bool st = (t + 1 < nt);
        // P1 (mh0, nh0): 12 reads + 4 B-stages
        readA(buf, 0); readB(buf, 0);
        if (st) { stageB(nbuf, 0); stageB(nbuf, 1); stageB(nbuf, 2); stageB(nbuf, 3); }
        BARX(); LGK0(); mma(0, 0); BARX();
        // P2 (mh0, nh1): 4 reads + 4 A-stages
        readB(buf, 1);
        if (st) { stageA(nbuf, 0); stageA(nbuf, 1); stageA(nbuf, 2); stageA(nbuf, 3); }
        BARX(); LGK0(); mma(0, 1); BARX();
        // P3 (mh1, nh1): 8 reads
        readA(buf, 1);
        BARX(); LGK0(); mma(1, 1); BARX();
        // P4 (mh1, nh0): 4 reads; wait covers loads issued >=2 phases ago
        readB(buf, 0);
        if (st) WAITV0();
        BARX(); LGK0(); mma(1, 0); BARX();
    }

    // ---- epilogue: bias + SiLU, f16 repack via LDS (buffers dead) ----
    f16* Cs = (f16*)smem;
#pragma unroll
    for (int mf = 0; mf < 8; ++mf)
#pragma unroll
        for (int nf = 0; nf < 4; ++nf) {
            int colL = wn * 64 + (nf >> 1) * 32 + (nf & 1) * 16 + l15;
            float bv = ga.bias[(int)brow0 + colL];
            int ch = colL >> 3, wi = colL & 7;
#pragma unroll
            for (int r = 0; r < 4; ++r) {
                int rowL = wm * 128 + (mf >> 2) * 64 + (mf & 3) * 16 + quad * 4 + r;
                float v = acc[mf][nf][r] + bv;
                if (SILU) v = v / (1.0f + __expf(-v));
                Cs[rowL * 256 + ((ch ^ (rowL & 31)) << 3) + wi] = (f16)v;
            }
        }
    __syncthreads();
    f16* Cout = (f16*)ga.C;
#pragma unroll
    for (int pass = 0; pass < 16; ++pass) {
        int s = pass * 512 + tid;
        int rowL = s >> 5, ch = s & 31;
        f16x8 v = *(const f16x8*)&Cs[rowL * 256 + ((ch ^ (rowL & 31)) << 3)];
        *(f16x8*)&Cout[(size_t)(arow0 + rowL) * ga.ldc + brow0 + ch * 8] = v;
    }
}

// ---------------------------------------------------------------------------
// Fused middle: e3 + a3 + b3 + Bu + Koopman + d1 -> h1d [B,1024] f16.
// (R10, verified best.)
// ---------------------------------------------------------------------------
__launch_bounds__(256)
__global__ void mid_k(const f16* __restrict__ cc2,
                      const f16* __restrict__ e_w3t, const float* __restrict__ e_b3,
                      const f16* __restrict__ a_w3t, const float* __restrict__ a_b3,
                      const f16* __restrict__ b_w3t, const float* __restrict__ b_b3,
                      const f16* __restrict__ d_w1t, const float* __restrict__ d_b1,
                      const float* __restrict__ u,   f16* __restrict__ h1d)
{
    __shared__ __align__(16) f16 As[32 * 64];
    __shared__ __align__(16) f16 Bs[128 * 64];
    __shared__ __align__(16) f16 zs[32 * 32];
    __shared__ float zb[32 * 32];
    __shared__ float ab[32 * 32];
    __shared__ float bu[32 * 32];
    __shared__ float ub[32 * 16];

    const int tid  = threadIdx.x;
    const int lane = tid & 63, wave = tid >> 6;
    const int l15 = lane & 15, quad = lane >> 4;
    const int r0 = blockIdx.x * 32;

    ub[tid]       = u[r0 * 16 + tid];
    ub[tid + 256] = u[r0 * 16 + 256 + tid];

    auto stage_d1 = [&](int ch) {
#pragma unroll
        for (int q = 0; q < 4; ++q) {
            int s = q * 256 + tid;
            int row = s >> 2, j = s & 3;
            int kseg = j ^ (row & 3);
            gld_lds16(d_w1t + (size_t)(ch * 256 + row) * 32 + kseg * 8,
                      &Bs[s * 8]);
        }
    };

#pragma unroll 1
    for (int ph = 0; ph < 2; ++ph) {
        const f16* W    = ph ? a_w3t : e_w3t;
        const float* bs = ph ? a_b3 : e_b3;
        const int K     = ph ? 256 : 1024;
        const int co    = ph ? 1024 : 0;
        float* ob       = ph ? ab : zb;
        f32x4 acc = {0.f, 0.f, 0.f, 0.f};
        for (int k0 = 0; k0 < K; k0 += 64) {
            {
                int row = tid >> 3, sg = (tid & 7) ^ (row & 7);
                gld_lds16(cc2 + (size_t)(r0 + row) * 1536 + co + k0 + sg * 8,
                          &As[tid * 8]);
            }
            {
                int row = tid >> 3, sg = (tid & 7) ^ (row & 7);
                gld_lds16(W + (size_t)row * K + k0 + sg * 8, &Bs[tid * 8]);
            }
            __syncthreads();
#pragma unroll
            for (int kk = 0; kk < 64; kk += 32) {
                int ar = ((wave >> 1) << 4) + l15;
                int ast = ((kk >> 3) + quad) ^ (ar & 7);
                f16x8 af = *(const f16x8*)&As[(ar * 8 + ast) * 8];
                int br = ((wave & 1) << 4) + l15;
                int bst = ((kk >> 3) + quad) ^ (br & 7);
                f16x8 bf = *(const f16x8*)&Bs[(br * 8 + bst) * 8];
                acc = __builtin_amdgcn_mfma_f32_16x16x32_f16(af, bf, acc, 0, 0, 0);
            }
            __syncthreads();
        }
#pragma unroll
        for (int r = 0; r < 4; ++r) {
            int row = ((wave >> 1) << 4) + quad * 4 + r;
            int col = ((wave & 1) << 4) + l15;
            ob[row * 32 + col] = acc[r] + bs[col];
        }
    }

#pragma unroll 1
    for (int ch = 0; ch < 4; ++ch) {
        f32x4 acc[2][2];
#pragma unroll
        for (int i = 0; i < 2; ++i)
#pragma unroll
            for (int j = 0; j < 2; ++j) acc[i][j] = f32x4{0.f, 0.f, 0.f, 0.f};
        for (int k0 = 0; k0 < 256; k0 += 64) {
            {   int row = tid >> 3, sg = (tid & 7) ^ (row & 7);
                gld_lds16(cc2 + (size_t)(r0 + row) * 1536 + 1280 + k0 + sg * 8,
                          &As[tid * 8]);
            }
#pragma unroll
            for (int it = 0; it < 4; ++it) {
                int s = it * 256 + tid;
                int row = s >> 3, sg = (s & 7) ^ (row & 7);
                gld_lds16(b_w3t + (size_t)(ch * 128 + row) * 256 + k0 + sg * 8,
                          &Bs[s * 8]);
            }
            __syncthreads();
#pragma unroll
            for (int kk = 0; kk < 64; kk += 32) {
                f16x8 af[2], bf[2];
#pragma unroll
                for (int i = 0; i < 2; ++i) {
                    int ar = i * 16 + l15;
                    int st = ((kk >> 3) + quad) ^ (ar & 7);
                    af[i] = *(const f16x8*)&As[(ar * 8 + st) * 8];
                }
#pragma unroll
                for (int j = 0; j < 2; ++j) {
                    int br = wave * 32 + j * 16 + l15;
                    int st = ((kk >> 3) + quad) ^ (br & 7);
                    bf[j] = *(const f16x8*)&Bs[(br * 8 + st) * 8];
                }
#pragma unroll
                for (int i = 0; i < 2; ++i)
#pragma unroll
                    for (int j = 0; j < 2; ++j)
                        acc[i][j] = __builtin_amdgcn_mfma_f32_16x16x32_f16(
                            af[i], bf[j], acc[i][j], 0, 0, 0);
            }
            __syncthreads();
        }
#pragma unroll
        for (int j = 0; j < 2; ++j) {
            int colg = ch * 128 + wave * 32 + j * 16 + l15;
            float bv = b_b3[colg];
            int z = colg >> 4;
#pragma unroll
            for (int i = 0; i < 2; ++i) {
#pragma unroll
                for (int r = 0; r < 4; ++r) {
                    int row = i * 16 + quad * 4 + r;
                    float v = (acc[i][j][r] + bv) * ub[row * 16 + l15];
                    v += __shfl_xor(v, 8, 16);
                    v += __shfl_xor(v, 4, 16);
                    v += __shfl_xor(v, 2, 16);
                    v += __shfl_xor(v, 1, 16);
                    if (l15 == 0) bu[row * 32 + z] = v;
                }
            }
        }
    }
    __syncthreads();

    stage_d1(0);
#pragma unroll
    for (int t = 0; t < 4; ++t) {
        int idx = t * 256 + tid;
        int row = idx >> 5, z = idx & 31;
        int pb = idx & ~1;
        float a  = ab[pb], b = ab[pb + 1];
        float z0 = zb[pb], z1 = zb[pb + 1];
        float f  = __expf(a * DT_C);
        float c_ = __cosf(b * DT_C);
        float s_ = __sinf(b * DT_C);
        float Az = (z & 1) ? f * (s_ * z0 + c_ * z1) : f * (c_ * z0 - s_ * z1);
        float zc = (z & 1) ? z1 : z0;
        f16 zv = (f16)(zc + DT_C * (Az + bu[idx]));
        zs[(row * 4 + ((z >> 3) ^ (row & 3))) * 8 + (z & 7)] = zv;
    }
    __syncthreads();

    f16x8 afD[2];
#pragma unroll
    for (int i = 0; i < 2; ++i) {
        int ar = i * 16 + l15;
        int ast = quad ^ (ar & 3);
        afD[i] = *(const f16x8*)&zs[(ar * 4 + ast) * 8];
    }
#pragma unroll 1
    for (int ch = 0; ch < 4; ++ch) {
        f32x4 accd[2][4];
#pragma unroll
        for (int n = 0; n < 4; ++n) {
            int br = wave * 64 + n * 16 + l15;
            int bst = quad ^ (br & 3);
            f16x8 bf = *(const f16x8*)&Bs[(br * 4 + bst) * 8];
#pragma unroll
            for (int i = 0; i < 2; ++i) {
                f32x4 zero = {0.f, 0.f, 0.f, 0.f};
                accd[i][n] = __builtin_amdgcn_mfma_f32_16x16x32_f16(
                    afD[i], bf, zero, 0, 0, 0);
            }
        }
        __syncthreads();
        if (ch < 3) stage_d1(ch + 1);
#pragma unroll
        for (int n = 0; n < 4; ++n) {
            int col = ch * 256 + wave * 64 + n * 16 + l15;
            float bv = d_b1[col];
#pragma unroll
            for (int i = 0; i < 2; ++i)
#pragma unroll
                for (int r = 0; r < 4; ++r) {
                    int row = i * 16 + quad * 4 + r;
                    float v = accd[i][n][r] + bv;
                    v = v / (1.0f + __expf(-v));
                    h1d[(size_t)(r0 + row) * 1024 + col] = (f16)v;
                }
        }
        if (ch < 3) __syncthreads();
    }
}

// ---------------------------------------------------------------------------
// One-shot prep: 13 weight transposes (f32 [K,N] -> f16 [N,K]), x f32->f16,
// L1 bias concat.
// ---------------------------------------------------------------------------
struct PrepArgs {
    const float* w[13];
    f16*         wt[13];
    int          K[13];
    int          N[13];
    const float* bsrc[3];
    float*       bias1;
    const float* x;
    f16*         xb;
};

__launch_bounds__(256)
__global__ void prep_k(PrepArgs pa, int ntrans, int ncvt)
{
    int bid = blockIdx.x;
    if (bid < ntrans) {
        int i = 0, t;
        for (;; ++i) {
            t = (pa.K[i] >> 5) * (pa.N[i] >> 5);
            if (bid < t) break;
            bid -= t;
        }
        const int K = pa.K[i], N = pa.N[i];
        const int tn = N >> 5;
        const int k0 = (bid / tn) << 5, n0 = (bid % tn) << 5;
        __shared__ float tbuf[32][33];
        const int tx = threadIdx.x & 31, ty = threadIdx.x >> 5;
        const float* src = pa.w[i];
        f16* dst = pa.wt[i];
#pragma unroll
        for (int r = 0; r < 32; r += 8)
            tbuf[ty + r][tx] = src[(size_t)(k0 + ty + r) * N + n0 + tx];
        __syncthreads();
#pragma unroll
        for (int r = 0; r < 32; r += 8)
            dst[(size_t)(n0 + ty + r) * K + k0 + tx] = (f16)tbuf[tx][ty + r];
    } else if (bid < ntrans + ncvt) {
        int i = ((bid - ntrans) * 256 + threadIdx.x) * 4;
        float4 v = *(const float4*)(pa.x + i);
        f16x4 o = {(f16)v.x, (f16)v.y, (f16)v.z, (f16)v.w};
        *(f16x4*)(pa.xb + i) = o;
    } else {
        int idx = (bid - ntrans - ncvt) * 256 + (int)threadIdx.x; // 0..1535
        float v = (idx < 1024) ? pa.bsrc[0][idx]
                : (idx < 1280) ? pa.bsrc[1][idx - 1024]
                               : pa.bsrc[2][idx - 1280];
        pa.bias1[idx] = v;
    }
}

extern "C" void kernel_launch(void* const* d_in, const int* in_sizes, int n_in,
                              void* d_out, int out_size, void* d_ws, size_t ws_size,
                              hipStream_t stream)
{
    (void)in_sizes; (void)n_in; (void)out_size; (void)ws_size;
    const float* x    = (const float*)d_in[0];
    const float* u    = (const float*)d_in[1];
    const float* e_w1 = (const float*)d_in[2];  const float* e_b1 = (const float*)d_in[3];
    const float* e_w2 = (const float*)d_in[4];  const float* e_b2 = (const float*)d_in[5];
    const float* e_w3 = (const float*)d_in[6];  const float* e_b3 = (const float*)d_in[7];
    const float* d_w1 = (const float*)d_in[8];  const float* d_b1 = (const float*)d_in[9];
    const float* d_w2 = (const float*)d_in[10]; const float* d_b2 = (const float*)d_in[11];
    const float* d_w3 = (const float*)d_in[12]; const float* d_b3 = (const float*)d_in[13];
    const float* d_w4 = (const float*)d_in[14]; const float* d_b4 = (const float*)d_in[15];
    const float* a_w1 = (const float*)d_in[16]; const float* a_b1 = (const float*)d_in[17];
    const float* a_w2 = (const float*)d_in[18]; const float* a_b2 = (const float*)d_in[19];
    const float* a_w3 = (const float*)d_in[20]; const float* a_b3 = (const float*)d_in[21];
    const float* b_w1 = (const float*)d_in[22]; const float* b_b1 = (const float*)d_in[23];
    const float* b_w2 = (const float*)d_in[24]; const float* b_b2 = (const float*)d_in[25];
    const float* b_w3 = (const float*)d_in[26]; const float* b_b3 = (const float*)d_in[27];

    char* p = (char*)d_ws;
    auto alloc = [&](size_t nbytes) -> void* {
        void* r = (void*)p;
        p += (nbytes + 255) & ~(size_t)255;
        return r;
    };
    // activations
    f16*   xb   = (f16*)  alloc((size_t)B_SZ * X_D * 2);
    f16*   cc1  = (f16*)  alloc((size_t)B_SZ * 1536 * 2);  // h1e | p1a | p1b
    f16*   cc2  = (f16*)  alloc((size_t)B_SZ * 1536 * 2);  // h2e | p2a | p2b
    // decoder ping-pong aliases (cc1/cc2 dead by then)
    f16*   h1d  = cc1;
    f16*   h2d  = cc2;
    f16*   h3d  = cc1;
    // transposed f16 weights [N][K]
    f16*   W1t   = (f16*)alloc((size_t)1536 * X_D * 2);    // e|a|b layer-1 stacked
    float* bias1 = (float*)alloc(1536 * 4);
    f16* e_w2t = (f16*)alloc((size_t)H_D * H_D * 2);
    f16* e_w3t = (f16*)alloc((size_t)Z_D * H_D * 2);
    f16* d_w1t = (f16*)alloc((size_t)H_D * Z_D * 2);
    f16* d_w2t = (f16*)alloc((size_t)H_D * H_D * 2);
    f16* d_w3t = (f16*)alloc((size_t)H_D * H_D * 2);
    f16* d_w4t = (f16*)alloc((size_t)X_D * H_D * 2);
    f16* a_w2t = (f16*)alloc((size_t)A_D * A_D * 2);
    f16* a_w3t = (f16*)alloc((size_t)Z_D * A_D * 2);
    f16* b_w2t = (f16*)alloc((size_t)A_D * A_D * 2);
    f16* b_w3t = (f16*)alloc((size_t)(Z_D * U_D) * A_D * 2);

    // ---- prep ----
    PrepArgs pa;
    const float* ws_[13] = {e_w1, e_w2, e_w3, d_w1, d_w2, d_w3, d_w4,
                            a_w1, a_w2, a_w3, b_w1, b_w2, b_w3};
    f16* wts_[13] = {W1t, e_w2t, e_w3t, d_w1t, d_w2t, d_w3t, d_w4t,
                     W1t + (size_t)1024 * X_D, a_w2t, a_w3t,
                     W1t + (size_t)1280 * X_D, b_w2t, b_w3t};
    int Ks_[13] = {X_D, H_D, H_D, Z_D, H_D, H_D, H_D, X_D, A_D, A_D, X_D, A_D, A_D};
    int Ns_[13] = {H_D, H_D, Z_D, H_D, H_D, H_D, X_D, A_D, A_D, Z_D, A_D, A_D, Z_D*U_D};
    int ntrans = 0;
    for (int i = 0; i < 13; ++i) {
        pa.w[i] = ws_[i]; pa.wt[i] = wts_[i]; pa.K[i] = Ks_[i]; pa.N[i] = Ns_[i];
        ntrans += (Ks_[i] >> 5) * (Ns_[i] >> 5);
    }
    pa.bsrc[0] = e_b1; pa.bsrc[1] = a_b1; pa.bsrc[2] = b_b1;
    pa.bias1 = bias1; pa.x = x; pa.xb = xb;
    const int ncvt = (B_SZ * X_D) / 1024;
    prep_k<<<ntrans + ncvt + 6, 256, 0, stream>>>(pa, ntrans, ncvt);

    auto G = [](const f16* A, const f16* W, const float* bias, void* C,
                int lda, int ldc, int K) {
        GArg g; g.A = A; g.W = W; g.bias = bias; g.C = C;
        g.lda = lda; g.ldc = ldc; g.K = K; return g;
    };
    GSet s;

    // ---- fused layer-1: [B,64] @ [64,1536] -> cc1 (K=64, old kernel) ----
    s.g[0] = G(xb, W1t, bias1, cc1, X_D, 1536, X_D);
    s.yn0 = 12; s.yn1 = 0;
    gemm_k<128,128,64,2,2,true,1><<<dim3(B_SZ/128, 12), 256, 0, stream>>>(s);

    // ---- merged layer-2 via m201-port: e2 (4 tiles) + a2 (1) + b2 (1) ----
    s.g[0] = G(cc1,        e_w2t, e_b2, cc2,        1536, 1536, H_D);
    s.g[1] = G(cc1 + 1024, a_w2t, a_b2, cc2 + 1024, 1536, 1536, A_D);
    s.g[2] = G(cc1 + 1280, b_w2t, b_b2, cc2 + 1280, 1536, 1536, A_D);
    s.yn0 = 4; s.yn1 = 1;
    gemm10_k<true><<<dim3(B_SZ/256, 6), 512, 0, stream>>>(s);

    // ---- fused middle: e3+a3+b3+Bu+Koopman+d1 -> h1d ----
    mid_k<<<B_SZ/32, 256, 0, stream>>>(cc2, e_w3t, e_b3, a_w3t, a_b3,
                                       b_w3t, b_b3, d_w1t, d_b1, u, h1d);

    // ---- decoder (d1 fused into mid_k) ----
    // d2/d3 via m201-port (grid 64x4 = 256 blocks = exactly 1/CU, 1 round)
    s.yn0 = 4; s.yn1 = 0;
    s.g[0] = G(h1d, d_w2t, d_b2, h2d, H_D, H_D, H_D);
    gemm10_k<true><<<dim3(B_SZ/256, 4), 512, 0, stream>>>(s);

    s.g[0] = G(h2d, d_w3t, d_b3, h3d, H_D, H_D, H_D);
    gemm10_k<true><<<dim3(B_SZ/256, 4), 512, 0, stream>>>(s);

    s.g[0] = G(h3d, d_w4t, d_b4, d_out, H_D, X_D, H_D);
    s.yn0 = 1;
    gemm_k<64,64,64,2,2,false,0><<<dim3(B_SZ/64, 1), 256, 0, stream>>>(s);
}